// Round 5
// baseline (181.911 us; speedup 1.0000x reference)
//
#include <hip/hip_runtime.h>
#include <cstdint>
#include <cstddef>

// Problem constants (fixed by the reference)
#define B_      32
#define N_      8400
#define C_      80
#define NC      672000        // N_*C_
#define NCV4    168000        // NC/4
#define NBINS   4096
#define TOPK    1024
#define MAXDET  300
#define CANDCAP 4096
#define NSLICE  16
#define SLICE_V4 10500        // NCV4 / NSLICE
#define NBKT    8             // score bins 4088..4095 (all x in [0.998..1))
#define SEGB    64            // per-(batch,bucket,slice) cap (mean 10.25, 17 sigma)
#define BSORT   256           // per-bucket cap (mean 164, 7.2 sigma)
#define CLS_CAP 256           // per-class NMS cap (matches rounds 0-4 behavior)

// Static stage threshold: score >= 4088/4096 = 0.998046875.
// Expected candidates/batch = 672000*8/4096 = 1312 (sd ~36). Bucket = bin-4088
// partitions candidates into 8 ORDER-DISJOINT groups (floor is monotone, float
// bits are monotone): buckets concatenated 7..0 == exact lax.top_k order
// (score desc, index asc via key low bits). Violating inputs take the exact
// in-kernel histogram fallback (never on bench input).
#define STAGE_THRESH 0.998046875f

// Workspace layout (bytes): only the stage->fused interface remains global.
#define WS_SEGKEYS  0           // 32*8*16*64*8 = 2097152
#define WS_SEGCNT   2097152     // 32*8*16*4    = 16384

// Output layout (float32, concatenated): boxes[32][300][4], scores[32][300],
// labels[32][300], n_valid[32]
#define OUT_SCORES  38400
#define OUT_LABELS  48000
#define OUT_NVALID  57600

// ---------------------------------------------------------------------------
// K1: single-pass filter+stage into PRIVATE per-(batch,bucket,slice) segments.
// key = (bits(v)<<32) | ~flat_idx. 8 LDS counters per block; plain global
// stores; no global atomics, no pre-zeroing (raw counts let K2 detect
// overflow -> fallback). Memory-bound: 86 MB read ~= 14 us (at roofline).
__global__ __launch_bounds__(256) void stage_kernel(const float4* __restrict__ scores4,
                                                    unsigned* __restrict__ segCnt,
                                                    unsigned long long* __restrict__ segKeys) {
    __shared__ unsigned lcnt[NBKT];
    int b = blockIdx.x, sl = blockIdx.y, tid = threadIdx.x;
    if (tid < NBKT) lcnt[tid] = 0;
    __syncthreads();
    const float4* s = scores4 + (size_t)b * NCV4 + (size_t)sl * SLICE_V4;
    for (int i = tid; i < SLICE_V4; i += 256) {
        float4 v = s[i];
        float c[4] = {v.x, v.y, v.z, v.w};
        unsigned flat0 = ((unsigned)sl * SLICE_V4 + (unsigned)i) * 4u;
        #pragma unroll
        for (int kc = 0; kc < 4; ++kc) {
            float x = (c[kc] > 0.001f) ? c[kc] : 0.0f;
            if (x >= STAGE_THRESH) {
                int bin = (int)(x * 4096.0f);             // exact: x * 2^12
                bin = bin > (NBINS - 1) ? (NBINS - 1) : bin;
                int bkt = bin - 4088;                      // 0..7
                unsigned p = atomicAdd(&lcnt[bkt], 1u);
                if (p < (unsigned)SEGB)
                    segKeys[(((size_t)(b * NBKT + bkt)) * NSLICE + sl) * SEGB + p] =
                        ((unsigned long long)__float_as_uint(x) << 32) |
                        (unsigned long long)(0xFFFFFFFFu - (flat0 + kc));
            }
        }
    }
    __syncthreads();
    if (tid < NBKT) segCnt[(b * NBKT + tid) * NSLICE + sl] = lcnt[tid];
}

// ---------------------------------------------------------------------------
// K2 (fused, per batch, 1024 threads = 16 waves): select -> box gather ->
// NMS -> finalize, all intermediates in LDS. Differs from the round-1 fusion
// (88.6 us) by replacing every component that made it slow:
//   - rank-and-scatter select (proven in rounds 2-4), 128 threads/bucket
//   - register extraction from packed clsv bytes (round-3 proven)
//   - WAVE-PARALLEL MASK-GREEDY NMS: m<=64 candidates live in lanes; per
//     pivot i: 5 shfl broadcasts + IoU + one ballot -> 64-bit over-mask;
//     greedy = m register-mask steps. Exactly equivalent to the sequential
//     greedy (keep i iff not in accumulated over-mask of kept rows).
//   - 2-barrier ballot/popcount scan finalize (round-2 proven)
// Exact fallbacks: in-block histogram+bitonic for invalid stage output;
// iterative greedy for classes with m>64. Neither taken on bench input.
__global__ __launch_bounds__(1024) void fused_kernel(
        const float4* __restrict__ scores4,
        const unsigned long long* __restrict__ segKeys,
        const unsigned* __restrict__ segCnt,
        const float4* __restrict__ boxes4,
        float* __restrict__ out) {
    __shared__ unsigned scnt2[NBKT * NSLICE];      // 512 B
    __shared__ unsigned bsum[NBKT];
    __shared__ unsigned bok[NBKT];
    __shared__ unsigned spref[NBKT][NSLICE];       // 512 B
    __shared__ float   sScore[TOPK];               // 4 KB
    __shared__ int     sBoxIdx[TOPK];              // 4 KB
    __shared__ __align__(16) unsigned char sClsv[TOPK];   // 1 KB (0x80|cls)
    __shared__ float4  sBox[TOPK];                 // 16 KB
    __shared__ unsigned char sKeep[TOPK];          // 1 KB
    __shared__ unsigned short sposW[16][CLS_CAP];  // 8 KB  (per-wave slots)
    __shared__ unsigned char  supW[16][CLS_CAP];   // 4 KB  (iterative path)
    __shared__ int wsum[16];
    __shared__ int sel[MAXDET];                    // 1.2 KB
    __shared__ int s_cut;
    __shared__ unsigned s_scnt;
    // pool: fast path uses kbuf[8][256] (16 KB) for rank; fallback uses
    // kbuf[4096] (32 KB) + fh[4096] (16 KB) as in rounds 0-1.
    __shared__ __align__(16) char upool[49152];
    unsigned long long* kbuf = (unsigned long long*)upool;
    unsigned* fh = (unsigned*)(upool + 32768);

    int b = blockIdx.x, tid = threadIdx.x;
    int lane = tid & 63, wave = tid >> 6;

    // ---- P0: counts, bucket sums, validity, slice prefixes.
    if (tid < NBKT * NSLICE) scnt2[tid] = segCnt[b * NBKT * NSLICE + tid];
    __syncthreads();
    if (tid < NBKT) {
        unsigned ssum = 0, ok = 1;
        #pragma unroll
        for (int sl = 0; sl < NSLICE; ++sl) {
            unsigned v = scnt2[tid * NSLICE + sl];
            if (v > (unsigned)SEGB) ok = 0;
            ssum += v;
        }
        bsum[tid] = ssum; bok[tid] = ok;
    }
    if (tid < NBKT * NSLICE) {
        int bkt = tid >> 4, sl = tid & 15;
        unsigned acc = 0;
        for (int s2 = 0; s2 < sl; ++s2) acc += scnt2[bkt * NSLICE + s2];
        spref[bkt][sl] = acc;
    }
    __syncthreads();
    unsigned M = 0; int valid = 1;                 // block-uniform
    #pragma unroll
    for (int t = 0; t < NBKT; ++t) {
        unsigned s2 = bsum[t];
        if (!bok[t] || s2 > (unsigned)BSORT) valid = 0;
        M += s2;
    }
    if (M < (unsigned)TOPK || M > (unsigned)CANDCAP) valid = 0;

    if (valid) {
        // ---- P1: gather segments into per-bucket kbuf regions (16 waves).
        for (int seg = wave; seg < NBKT * NSLICE; seg += 16) {
            int bkt = seg >> 4, sl = seg & 15;
            unsigned c2 = scnt2[seg];              // <= SEGB
            if ((unsigned)lane < c2)
                kbuf[bkt * BSORT + spref[bkt][sl] + lane] =
                    segKeys[(((size_t)(b * NBKT + bkt)) * NSLICE + sl) * SEGB + lane];
        }
        __syncthreads();
        // ---- P2: rank-and-scatter (128 threads/bucket, 2 keys each).
        // M >= 1024 => positions [0,1024) are exactly covered.
        int bkt = tid >> 7;
        unsigned n = bsum[bkt];
        unsigned base = 0;
        for (int t = bkt + 1; t < NBKT; ++t) base += bsum[t];
        if (base < (unsigned)TOPK && n > 0) {
            const unsigned long long* kb = kbuf + bkt * BSORT;
            int j0 = tid & 127, j1 = j0 + 128;
            unsigned long long k0 = (j0 < (int)n) ? kb[j0] : 0ull;
            unsigned long long k1 = (j1 < (int)n) ? kb[j1] : 0ull;
            unsigned r0 = 0, r1 = 0;
            for (unsigned i = 0; i < n; ++i) {
                unsigned long long ki = kb[i];
                r0 += (ki > k0); r1 += (ki > k1);
            }
            if (j0 < (int)n) {
                unsigned pos = base + r0;
                if (pos < (unsigned)TOPK) {
                    unsigned idx = 0xFFFFFFFFu - (unsigned)(k0 & 0xFFFFFFFFull);
                    if (idx >= (unsigned)NC) idx = 0;    // defensive
                    unsigned bi = idx / (unsigned)C_;
                    sScore[pos] = __uint_as_float((unsigned)(k0 >> 32));
                    sClsv[pos] = (unsigned char)(0x80u | (idx - bi * (unsigned)C_));
                    sBoxIdx[pos] = (int)bi;
                }
            }
            if (j1 < (int)n) {
                unsigned pos = base + r1;
                if (pos < (unsigned)TOPK) {
                    unsigned idx = 0xFFFFFFFFu - (unsigned)(k1 & 0xFFFFFFFFull);
                    if (idx >= (unsigned)NC) idx = 0;
                    unsigned bi = idx / (unsigned)C_;
                    sScore[pos] = __uint_as_float((unsigned)(k1 >> 32));
                    sClsv[pos] = (unsigned char)(0x80u | (idx - bi * (unsigned)C_));
                    sBoxIdx[pos] = (int)bi;
                }
            }
        }
    } else {
        // ---- exact fallback (never on bench): histogram cut + bitonic.
        for (int i = tid; i < NBINS; i += 1024) fh[i] = 0;
        if (tid == 0) s_scnt = 0;
        __syncthreads();
        const float4* s = scores4 + (size_t)b * NCV4;
        for (int i = tid; i < NCV4; i += 1024) {
            float4 v = s[i];
            float c4[4] = {v.x, v.y, v.z, v.w};
            #pragma unroll
            for (int kc = 0; kc < 4; ++kc) {
                float x = (c4[kc] > 0.001f) ? c4[kc] : 0.0f;
                int bin = (int)(x * 4096.0f);
                bin = bin > (NBINS - 1) ? (NBINS - 1) : bin;
                atomicAdd(&fh[bin], 1u);
            }
        }
        __syncthreads();
        if (tid == 0) {
            unsigned acc = 0; int cb2 = 0;
            for (int bin = NBINS - 1; bin >= 0; --bin) {
                acc += fh[bin];
                if (acc >= (unsigned)TOPK) { cb2 = bin; break; }
            }
            s_cut = cb2;
        }
        __syncthreads();
        int cb = s_cut;
        for (int i = tid; i < NCV4; i += 1024) {
            float4 v = s[i];
            float c4[4] = {v.x, v.y, v.z, v.w};
            unsigned flat0 = (unsigned)i * 4u;
            #pragma unroll
            for (int kc = 0; kc < 4; ++kc) {
                float x = (c4[kc] > 0.001f) ? c4[kc] : 0.0f;
                int bin = (int)(x * 4096.0f);
                bin = bin > (NBINS - 1) ? (NBINS - 1) : bin;
                if (bin >= cb) {
                    unsigned p = atomicAdd(&s_scnt, 1u);
                    if (p < (unsigned)CANDCAP)
                        kbuf[p] = ((unsigned long long)__float_as_uint(x) << 32) |
                                  (unsigned long long)(0xFFFFFFFFu - (flat0 + kc));
                }
            }
        }
        __syncthreads();
        unsigned M2 = s_scnt; if (M2 > (unsigned)CANDCAP) M2 = CANDCAP;
        int S = (M2 <= 1024u) ? 1024 : (M2 <= 2048u ? 2048 : CANDCAP);
        for (int i = (int)M2 + tid; i < S; i += 1024) kbuf[i] = 0ull;
        __syncthreads();
        for (int kk = 2; kk <= S; kk <<= 1) {
            for (int j = kk >> 1; j > 0; j >>= 1) {
                for (int t = tid; t < S; t += 1024) {
                    int l = t ^ j;
                    if (l > t) {
                        unsigned long long a0 = kbuf[t], c0 = kbuf[l];
                        bool sw = ((t & kk) == 0) ? (a0 < c0) : (a0 > c0);
                        if (sw) { kbuf[t] = c0; kbuf[l] = a0; }
                    }
                }
                __syncthreads();
            }
        }
        for (int r = tid; r < TOPK; r += 1024) {
            unsigned long long key = kbuf[r];
            float sc = __uint_as_float((unsigned)(key >> 32));
            unsigned idx = 0xFFFFFFFFu - (unsigned)(key & 0xFFFFFFFFull);
            if (idx >= (unsigned)NC) idx = 0;
            unsigned bi = idx / (unsigned)C_;
            sScore[r] = sc;
            sClsv[r] = (unsigned char)((sc > 0.001f ? 0x80u : 0u) |
                                       (idx - bi * (unsigned)C_));
            sBoxIdx[r] = (int)bi;
        }
    }
    __syncthreads();

    // ---- P3: box gather (1024 independent random 16B loads) + keep init.
    sBox[tid] = boxes4[(size_t)b * N_ + sBoxIdx[tid]];
    sKeep[tid] = 0;
    __syncthreads();

    // ---- P4: NMS. wave w handles classes w, w+16, ... (5 each). Cross-class
    // IoU is exactly 0 (offset gap 4096 >> max box 640) => per-class greedy
    // == reference's global sequential loop. IoU f32 with __fmul_rn (no FMA).
    for (int c = wave; c < C_; c += 16) {
        unsigned target = 0x80u | (unsigned)c;
        // register extraction: lane's 16 consecutive clsv bytes (4 LDS uints)
        unsigned d0 = ((const unsigned*)sClsv)[lane * 4 + 0];
        unsigned d1 = ((const unsigned*)sClsv)[lane * 4 + 1];
        unsigned d2 = ((const unsigned*)sClsv)[lane * 4 + 2];
        unsigned d3 = ((const unsigned*)sClsv)[lane * 4 + 3];
        unsigned mmask = 0; int cnt = 0;
        #pragma unroll
        for (int t = 0; t < 16; ++t) {
            unsigned d = (t < 4) ? d0 : (t < 8) ? d1 : (t < 12) ? d2 : d3;
            unsigned v = (d >> ((t & 3) * 8)) & 0xffu;
            if (v == target) { mmask |= (1u << t); ++cnt; }
        }
        int x = cnt;                                 // inclusive wave prefix
        #pragma unroll
        for (int o = 1; o < 64; o <<= 1) {
            int y = __shfl_up(x, o, 64);
            if (lane >= o) x += y;
        }
        int pre = x - cnt;
        int m = __shfl(x, 63, 64);
        int slot = pre;
        #pragma unroll
        for (int t = 0; t < 16; ++t) {
            if ((mmask >> t) & 1u) {
                if (slot < CLS_CAP) sposW[wave][slot] = (unsigned short)(lane * 16 + t);
                ++slot;
            }
        }
        int m2 = m < CLS_CAP ? m : CLS_CAP;
        __threadfence_block();                       // sposW visible in-wave
        float off = (float)c * 4096.0f;              // exact
        if (m2 <= 64) {
            // ---- mask-greedy: candidate j lives in lane j.
            float y1 = 0, x1 = 0, y2 = 0, x2 = 0, ar = 0; int p = 0;
            if (lane < m2) {
                p = sposW[wave][lane];
                float4 tb = sBox[p];
                y1 = tb.x + off; x1 = tb.y + off;
                y2 = tb.z + off; x2 = tb.w + off;
                ar = __fmul_rn((x2 - x1) + 1.0f, (y2 - y1) + 1.0f);
            }
            unsigned long long sup = 0, keepm = 0;
            for (int i = 0; i < m2; ++i) {
                if ((sup >> i) & 1ull) continue;     // uniform branch
                keepm |= 1ull << i;
                float cy1 = __shfl(y1, i, 64), cx1 = __shfl(x1, i, 64);
                float cy2 = __shfl(y2, i, 64), cx2 = __shfl(x2, i, 64);
                float ca  = __shfl(ar, i, 64);
                bool over = false;
                if (lane < m2 && lane > i) {
                    float yy1 = fmaxf(cy1, y1), xx1 = fmaxf(cx1, x1);
                    float yy2 = fminf(cy2, y2), xx2 = fminf(cx2, x2);
                    float w2 = fmaxf(0.0f, (xx2 - xx1) + 1.0f);
                    float h2 = fmaxf(0.0f, (yy2 - yy1) + 1.0f);
                    float inter = __fmul_rn(w2, h2);
                    float denom = (ca + ar) - inter;
                    over = inter / denom > 0.7f;
                }
                sup |= __ballot(over);
            }
            if (lane < m2 && ((keepm >> lane) & 1ull)) sKeep[p] = 1;
        } else {
            // ---- iterative greedy (m>64; never on bench input).
            for (int j = lane; j < m2; j += 64) supW[wave][j] = 0;
            __threadfence_block();
            int cur = 0;
            while (cur < m2) {
                int pc = sposW[wave][cur];
                if (lane == 0) sKeep[pc] = 1;
                float4 cb4 = sBox[pc];
                float cy1 = cb4.x + off, cx1 = cb4.y + off;
                float cy2 = cb4.z + off, cx2 = cb4.w + off;
                float ca = __fmul_rn((cx2 - cx1) + 1.0f, (cy2 - cy1) + 1.0f);
                for (int j = cur + 1 + lane; j < m2; j += 64) {
                    if (!supW[wave][j]) {
                        float4 tb = sBox[sposW[wave][j]];
                        float y1 = tb.x + off, x1 = tb.y + off;
                        float y2 = tb.z + off, x2 = tb.w + off;
                        float arj = __fmul_rn((x2 - x1) + 1.0f, (y2 - y1) + 1.0f);
                        float yy1 = fmaxf(cy1, y1), xx1 = fmaxf(cx1, x1);
                        float yy2 = fminf(cy2, y2), xx2 = fminf(cx2, x2);
                        float w2 = fmaxf(0.0f, (xx2 - xx1) + 1.0f);
                        float h2 = fmaxf(0.0f, (yy2 - yy1) + 1.0f);
                        float inter = __fmul_rn(w2, h2);
                        float denom = (ca + arj) - inter;
                        if (inter / denom > 0.7f) supW[wave][j] = 1;
                    }
                }
                __threadfence_block();
                int nxt = m2;
                for (int j = cur + 1 + lane; j < m2; j += 64)
                    if (!supW[wave][j]) { nxt = j; break; }
                for (int o = 32; o > 0; o >>= 1) {
                    int other = __shfl_xor(nxt, o, 64);
                    nxt = nxt < other ? nxt : other;
                }
                cur = nxt;
            }
        }
    }
    __syncthreads();

    // ---- P5: stable top-300 (kept in order, then suppressed in order —
    // matches lax.top_k tie-break). 2-barrier ballot/popcount scan.
    int kp = sKeep[tid];
    unsigned long long mb = __ballot(kp != 0);
    int wpre = __popcll(mb & ((1ull << lane) - 1ull));
    if (lane == 0) wsum[wave] = __popcll(mb);
    __syncthreads();
    int wbase = 0, nk = 0;
    #pragma unroll
    for (int t = 0; t < 16; ++t) {
        int v = wsum[t];
        if (t < wave) wbase += v;
        nk += v;
    }
    int kexcl = wbase + wpre;    // exclusive kept rank
    int sexcl = tid - kexcl;     // exclusive suppressed rank
    if (kp) {
        if (kexcl < MAXDET) sel[kexcl] = tid;
    } else {
        int slot2 = nk + sexcl;
        if (slot2 < MAXDET) sel[slot2] = tid;
    }
    __syncthreads();
    if (tid < MAXDET) {
        int p = sel[tid];
        float sc = (tid < nk) ? sScore[p] : 0.0f;
        float4 tb = sBox[p];
        float* ob = out + ((size_t)b * MAXDET + tid) * 4;
        ob[0] = tb.x; ob[1] = tb.y; ob[2] = tb.z; ob[3] = tb.w;
        out[OUT_SCORES + b * MAXDET + tid] = sc;
        out[OUT_LABELS + b * MAXDET + tid] = (float)(sClsv[p] & 0x7f);
    }
    if (tid == 0) out[OUT_NVALID + b] = (float)(nk < MAXDET ? nk : MAXDET);
}

// ---------------------------------------------------------------------------
extern "C" void kernel_launch(void* const* d_in, const int* in_sizes, int n_in,
                              void* d_out, int out_size, void* d_ws, size_t ws_size,
                              hipStream_t stream) {
    const float* boxes  = (const float*)d_in[0];   // (32, 8400, 4)
    const float* scores = (const float*)d_in[1];   // (32, 8400, 80)
    float* out = (float*)d_out;
    char* ws = (char*)d_ws;

    unsigned long long* segKeys = (unsigned long long*)(ws + WS_SEGKEYS);
    unsigned* segCnt = (unsigned*)(ws + WS_SEGCNT);

    const float4* scores4 = (const float4*)scores;
    const float4* boxes4  = (const float4*)boxes;

    stage_kernel<<<dim3(B_, NSLICE), 256, 0, stream>>>(scores4, segCnt, segKeys);
    fused_kernel<<<B_, 1024, 0, stream>>>(scores4, segKeys, segCnt, boxes4, out);
}